// Round 1
// baseline (1500.524 us; speedup 1.0000x reference)
//
#include <hip/hip_runtime.h>
#include <math.h>

// ===================== small utility kernels =====================

__global__ void k_pad(const float* __restrict__ src, int sr, int sc,
                      float* __restrict__ dst, int dr, int dc) {
  int t = blockIdx.x*blockDim.x + threadIdx.x;
  if (t >= dr*dc) return;
  int r = t/dc, c = t - r*dc;
  dst[t] = (r < sr && c < sc) ? src[r*sc + c] : 0.f;
}

__global__ void k_deg(const int* __restrict__ dst, int E, int nsl, int* __restrict__ deg) {
  int t = blockIdx.x*blockDim.x + threadIdx.x;
  if (t >= E + nsl) return;
  int d = (t < E) ? dst[t] : (t - E);
  atomicAdd(&deg[d], 1);
}

__global__ __launch_bounds__(256)
void k_scan_block(const int* __restrict__ deg, int n, int* __restrict__ out, int* __restrict__ btot) {
  __shared__ int sh[256];
  int tid = threadIdx.x;
  int base = blockIdx.x*1024 + tid*4;
  int v0 = (base+0<n)?deg[base+0]:0;
  int v1 = (base+1<n)?deg[base+1]:0;
  int v2 = (base+2<n)?deg[base+2]:0;
  int v3 = (base+3<n)?deg[base+3]:0;
  int s = v0+v1+v2+v3;
  sh[tid] = s; __syncthreads();
  for (int o = 1; o < 256; o <<= 1) {
    int t = (tid >= o) ? sh[tid-o] : 0;
    __syncthreads();
    sh[tid] += t;
    __syncthreads();
  }
  if (tid == 255) btot[blockIdx.x] = sh[255];
  int run = sh[tid] - s;
  if (base+0<n) { out[base+0]=run; run+=v0; }
  if (base+1<n) { out[base+1]=run; run+=v1; }
  if (base+2<n) { out[base+2]=run; run+=v2; }
  if (base+3<n) { out[base+3]=run; run+=v3; }
}

__global__ __launch_bounds__(512)
void k_scan_tot(int* __restrict__ btot, int nb) {
  __shared__ int sh[512];
  int tid = threadIdx.x;
  int v = (tid < nb) ? btot[tid] : 0;
  sh[tid] = v; __syncthreads();
  for (int o = 1; o < 512; o <<= 1) {
    int t = (tid >= o) ? sh[tid-o] : 0;
    __syncthreads();
    sh[tid] += t;
    __syncthreads();
  }
  if (tid < nb) btot[tid] = sh[tid] - v;
}

__global__ void k_scan_add(int* __restrict__ rowptr, const int* __restrict__ btot, int n, int total) {
  int t = blockIdx.x*blockDim.x + threadIdx.x;
  if (t < n) rowptr[t] += btot[t >> 10];
  if (t == 0) rowptr[n] = total;
}

__global__ void k_fill(const int* __restrict__ src, const int* __restrict__ dst, int E, int nsl,
                       int* __restrict__ cursor, const int* __restrict__ rowptr, int* __restrict__ csr) {
  int t = blockIdx.x*blockDim.x + threadIdx.x;
  if (t >= E + nsl) return;
  int s, d;
  if (t < E) { s = src[t]; d = dst[t]; } else { s = t - E; d = s; }
  int slot = rowptr[d] + atomicAdd(&cursor[d], 1);
  csr[slot] = s;
}

// ===================== GIN (drug) =====================
// xin[d, f] = x[d, f] + sum_{s in in(d)} x[s, f];  pads f in [F, ds) with 0.
__global__ void k_gin_gather(const int* __restrict__ rowptr, const int* __restrict__ csr,
                             const float* __restrict__ x, int xs, int F,
                             float* __restrict__ xin, int ds, int n) {
  int t = blockIdx.x*blockDim.x + threadIdx.x;
  if (t >= n*ds) return;
  int d = t/ds, f = t - d*ds;
  if (f >= F) { xin[t] = 0.f; return; }
  float acc = x[(size_t)d*xs + f];
  int e1 = rowptr[d+1];
  for (int j = rowptr[d]; j < e1; ++j) acc += x[(size_t)csr[j]*xs + f];
  xin[t] = acc;
}

__global__ __launch_bounds__(384)
void k_drug_pool(const float* __restrict__ reps, float* __restrict__ xd) {
  int b = blockIdx.x, c = threadIdx.x;
  float m = -3.0e38f;
  const float* p = reps + (size_t)b*40*384 + c;
  for (int i = 0; i < 40; ++i) m = fmaxf(m, p[(size_t)i*384]);
  xd[(size_t)b*384 + c] = m;
}

// ===================== GEMM (f32, tiled 64x64, optional split-K atomics) =====================
// Requirements (all launches satisfy): M%64==0 via grid.y, N%64==0 via grid.x, Kchunk%32==0.
template<int ACT, int ATOMIC>   // ACT: 0 none, 1 relu, 2 elu (non-atomic path only)
__global__ __launch_bounds__(256)
void k_gemm(const float* __restrict__ A, int lda,
            const float* __restrict__ B, int ldb,
            const float* __restrict__ bias,
            float* __restrict__ C, int ldc, int Kchunk) {
  __shared__ __align__(16) float As[32][68];   // As[k][m] (transposed for b128 reads)
  __shared__ __align__(16) float Bs[32][68];   // Bs[k][n]
  const int tid = threadIdx.x;
  const int tx = tid & 15, ty = tid >> 4;
  const int row0 = blockIdx.y << 6, col0 = blockIdx.x << 6;
  const int kb = blockIdx.z * Kchunk;
  float acc[4][4] = {{0.f}};
  for (int k0 = 0; k0 < Kchunk; k0 += 32) {
#pragma unroll
    for (int i = 0; i < 2; ++i) {
      int idx = tid + (i << 8);
      int r = idx >> 3, c = (idx & 7) << 2;
      float4 v = *(const float4*)(A + (size_t)(row0 + r)*lda + (kb + k0 + c));
      As[c+0][r]=v.x; As[c+1][r]=v.y; As[c+2][r]=v.z; As[c+3][r]=v.w;
    }
#pragma unroll
    for (int i = 0; i < 2; ++i) {
      int idx = tid + (i << 8);
      int r = idx >> 4, c = (idx & 15) << 2;
      *(float4*)&Bs[r][c] = *(const float4*)(B + (size_t)(kb + k0 + r)*ldb + (col0 + c));
    }
    __syncthreads();
#pragma unroll
    for (int kk = 0; kk < 32; ++kk) {
      float4 av = *(const float4*)&As[kk][ty << 2];
      float4 bv = *(const float4*)&Bs[kk][tx << 2];
      acc[0][0]=fmaf(av.x,bv.x,acc[0][0]); acc[0][1]=fmaf(av.x,bv.y,acc[0][1]);
      acc[0][2]=fmaf(av.x,bv.z,acc[0][2]); acc[0][3]=fmaf(av.x,bv.w,acc[0][3]);
      acc[1][0]=fmaf(av.y,bv.x,acc[1][0]); acc[1][1]=fmaf(av.y,bv.y,acc[1][1]);
      acc[1][2]=fmaf(av.y,bv.z,acc[1][2]); acc[1][3]=fmaf(av.y,bv.w,acc[1][3]);
      acc[2][0]=fmaf(av.z,bv.x,acc[2][0]); acc[2][1]=fmaf(av.z,bv.y,acc[2][1]);
      acc[2][2]=fmaf(av.z,bv.z,acc[2][2]); acc[2][3]=fmaf(av.z,bv.w,acc[2][3]);
      acc[3][0]=fmaf(av.w,bv.x,acc[3][0]); acc[3][1]=fmaf(av.w,bv.y,acc[3][1]);
      acc[3][2]=fmaf(av.w,bv.z,acc[3][2]); acc[3][3]=fmaf(av.w,bv.w,acc[3][3]);
    }
    __syncthreads();
  }
  if (ATOMIC) {
#pragma unroll
    for (int i = 0; i < 4; ++i) {
      int r = row0 + (ty<<2) + i, c = col0 + (tx<<2);
#pragma unroll
      for (int j = 0; j < 4; ++j) atomicAdd(&C[(size_t)r*ldc + c + j], acc[i][j]);
    }
  } else {
#pragma unroll
    for (int i = 0; i < 4; ++i) {
      int r = row0 + (ty<<2) + i, c = col0 + (tx<<2);
      float4 v = make_float4(acc[i][0], acc[i][1], acc[i][2], acc[i][3]);
      if (bias) { v.x += bias[c]; v.y += bias[c+1]; v.z += bias[c+2]; v.w += bias[c+3]; }
      if (ACT == 1) { v.x=fmaxf(v.x,0.f); v.y=fmaxf(v.y,0.f); v.z=fmaxf(v.z,0.f); v.w=fmaxf(v.w,0.f); }
      else if (ACT == 2) {
        v.x = v.x>0.f?v.x:expm1f(v.x); v.y = v.y>0.f?v.y:expm1f(v.y);
        v.z = v.z>0.f?v.z:expm1f(v.z); v.w = v.w>0.f?v.w:expm1f(v.w);
      }
      *(float4*)(C + (size_t)r*ldc + c) = v;
    }
  }
}

template<int ACT>
__global__ void k_bias_act(float* __restrict__ C, int ldc, const float* __restrict__ bias, int M, int N) {
  int t = blockIdx.x*blockDim.x + threadIdx.x;
  if (t >= M*N) return;
  int r = t / N, c = t - r*N;
  float v = C[(size_t)r*ldc + c] + bias[c];
  if (ACT == 1) v = fmaxf(v, 0.f);
  else if (ACT == 2) v = v > 0.f ? v : expm1f(v);
  C[(size_t)r*ldc + c] = v;
}

// ===================== BatchNorm =====================
__global__ __launch_bounds__(256)
void k_bn_stats(const float* __restrict__ x, int rows, int cols, float* __restrict__ acc) {
  __shared__ float sh[256], sh2[256];
  int tid = threadIdx.x;
  int nth = gridDim.x * 256;
  int t = blockIdx.x*256 + tid;
  int c = t % cols;
  int r0 = t / cols;
  int rstep = nth / cols;        // launches guarantee nth % cols == 0
  float s = 0.f, s2 = 0.f;
  for (int r = r0; r < rows; r += rstep) {
    float v = x[(size_t)r*cols + c];
    s += v; s2 = fmaf(v, v, s2);
  }
  sh[tid] = s; sh2[tid] = s2; __syncthreads();
  for (int o = 128; o >= cols; o >>= 1) {
    if (tid < o) { sh[tid] += sh[tid+o]; sh2[tid] += sh2[tid+o]; }
    __syncthreads();
  }
  if (tid < cols) { atomicAdd(&acc[tid], sh[tid]); atomicAdd(&acc[cols+tid], sh2[tid]); }
}

__global__ void k_bn_apply(const float* __restrict__ x, int xs,
                           float* __restrict__ y, int ys,
                           const float* __restrict__ acc, float invn,
                           const float* __restrict__ g, const float* __restrict__ be,
                           int total, int cols) {
  int t = blockIdx.x*blockDim.x + threadIdx.x;
  if (t >= total) return;
  int c = t % cols;
  int r = t / cols;
  float mu = acc[c] * invn;
  float var = fmaxf(acc[cols+c]*invn - mu*mu, 0.f);
  float rstd = rsqrtf(var + 1e-5f);
  float v = (x[(size_t)r*xs + c] - mu) * rstd;
  if (g) v = fmaf(v, g[c], be[c]);
  y[(size_t)r*ys + c] = v;
}

// ===================== GAT =====================
__global__ void k_gat_node(const float* __restrict__ x, int K,
                           const float* __restrict__ W,
                           const float* __restrict__ as_, const float* __restrict__ ad_,
                           float* __restrict__ h, float* __restrict__ ssrc, float* __restrict__ sdst,
                           int n) {
  int i = blockIdx.x*blockDim.x + threadIdx.x;
  if (i >= n) return;
  float hv[16];
#pragma unroll
  for (int k = 0; k < 16; ++k) hv[k] = 0.f;
  for (int j = 0; j < K; ++j) {
    float xv = x[(size_t)i*K + j];
#pragma unroll
    for (int k = 0; k < 16; ++k) hv[k] = fmaf(xv, W[j*16 + k], hv[k]);
  }
  float s1 = 0.f, s2 = 0.f;
#pragma unroll
  for (int k = 0; k < 16; ++k) { s1 = fmaf(hv[k], as_[k], s1); s2 = fmaf(hv[k], ad_[k], s2); }
  float4* hp = (float4*)(h + (size_t)i*16);
  hp[0] = make_float4(hv[0],hv[1],hv[2],hv[3]);
  hp[1] = make_float4(hv[4],hv[5],hv[6],hv[7]);
  hp[2] = make_float4(hv[8],hv[9],hv[10],hv[11]);
  hp[3] = make_float4(hv[12],hv[13],hv[14],hv[15]);
  ssrc[i] = s1; sdst[i] = s2;
}

// Per-node: softmax-weighted aggregation over in-edges (CSR), + bias, relu,
// then cluster segment-max via bit-cast int atomicMax (valid: values >= 0).
__global__ void k_gat_gather_pool(const int* __restrict__ rowptr, const int* __restrict__ csr,
                                  const float* __restrict__ ssrc, const float* __restrict__ sdst,
                                  const float* __restrict__ h, const float* __restrict__ bias,
                                  const int* __restrict__ cluster,
                                  float* __restrict__ pooled, int n) {
  int d = blockIdx.x*blockDim.x + threadIdx.x;
  if (d >= n) return;
  float sd = sdst[d];
  float acc[16];
#pragma unroll
  for (int k = 0; k < 16; ++k) acc[k] = 0.f;
  float sum = 0.f;
  int e1 = rowptr[d+1];
  for (int j = rowptr[d]; j < e1; ++j) {
    int s = csr[j];
    float l = ssrc[s] + sd;
    l = (l > 0.f) ? l : 0.2f*l;
    float e = expf(l);                 // no max-subtraction: ratios identical, f32-safe
    sum += e;
    const float4* hp = (const float4*)(h + (size_t)s*16);
    float4 a = hp[0], b = hp[1], c = hp[2], dd = hp[3];
    acc[0]=fmaf(e,a.x,acc[0]);  acc[1]=fmaf(e,a.y,acc[1]);  acc[2]=fmaf(e,a.z,acc[2]);  acc[3]=fmaf(e,a.w,acc[3]);
    acc[4]=fmaf(e,b.x,acc[4]);  acc[5]=fmaf(e,b.y,acc[5]);  acc[6]=fmaf(e,b.z,acc[6]);  acc[7]=fmaf(e,b.w,acc[7]);
    acc[8]=fmaf(e,c.x,acc[8]);  acc[9]=fmaf(e,c.y,acc[9]);  acc[10]=fmaf(e,c.z,acc[10]); acc[11]=fmaf(e,c.w,acc[11]);
    acc[12]=fmaf(e,dd.x,acc[12]); acc[13]=fmaf(e,dd.y,acc[13]); acc[14]=fmaf(e,dd.z,acc[14]); acc[15]=fmaf(e,dd.w,acc[15]);
  }
  float inv = 1.f / sum;
  int* pp = (int*)(pooled + (size_t)cluster[d]*16);
#pragma unroll
  for (int k = 0; k < 16; ++k) {
    float v = fmaf(acc[k], inv, bias[k]);
    v = fmaxf(v, 0.f);
    atomicMax(&pp[k], __float_as_int(v));
  }
}

// ===================== final GEMV =====================
__global__ __launch_bounds__(64)
void k_gemv_out(const float* __restrict__ A, const float* __restrict__ w,
                const float* __restrict__ b, float* __restrict__ out) {
  int r = blockIdx.x, l = threadIdx.x;
  float s = 0.f;
  for (int k = l; k < 384; k += 64) s = fmaf(A[(size_t)r*384 + k], w[k], s);
#pragma unroll
  for (int o = 32; o > 0; o >>= 1) s += __shfl_down(s, o);
  if (l == 0) out[r] = s + b[0];
}

// ===================== host orchestration =====================
extern "C" void kernel_launch(void* const* d_in, const int* in_sizes, int n_in,
                              void* d_out, int out_size, void* d_ws, size_t ws_size,
                              hipStream_t stream) {
  (void)n_in; (void)out_size;
  const int B = 512, N0 = 706, C1v = 512, C2v = 400;
  const int nd  = B*40;       // 20480 drug nodes
  const int nc0 = B*N0;       // 361472
  const int nc1 = B*C1v;      // 262144
  const int nc2 = B*C2v;      // 204800
  const int Ed  = in_sizes[40]/2;
  const int Ec0 = in_sizes[42]/2;
  const int Ec1 = in_sizes[43]/2;

  const float* drug_x = (const float*)d_in[0];
  const float* cell_x = (const float*)d_in[1];
  const float* gW1[3] = {(const float*)d_in[2],(const float*)d_in[8],(const float*)d_in[14]};
  const float* gb1[3] = {(const float*)d_in[3],(const float*)d_in[9],(const float*)d_in[15]};
  const float* gW2[3] = {(const float*)d_in[4],(const float*)d_in[10],(const float*)d_in[16]};
  const float* gb2[3] = {(const float*)d_in[5],(const float*)d_in[11],(const float*)d_in[17]};
  const float* gg [3] = {(const float*)d_in[6],(const float*)d_in[12],(const float*)d_in[18]};
  const float* gbe[3] = {(const float*)d_in[7],(const float*)d_in[13],(const float*)d_in[19]};
  const float* demb_W = (const float*)d_in[20]; const float* demb_b = (const float*)d_in[21];
  const float* gatW[2]  = {(const float*)d_in[22],(const float*)d_in[26]};
  const float* gatAS[2] = {(const float*)d_in[23],(const float*)d_in[27]};
  const float* gatAD[2] = {(const float*)d_in[24],(const float*)d_in[28]};
  const float* gatB[2]  = {(const float*)d_in[25],(const float*)d_in[29]};
  const float* cembW1 = (const float*)d_in[30]; const float* cembb1 = (const float*)d_in[31];
  const float* cembW2 = (const float*)d_in[32]; const float* cembb2 = (const float*)d_in[33];
  const float* regW1 = (const float*)d_in[34]; const float* regb1 = (const float*)d_in[35];
  const float* regW2 = (const float*)d_in[36]; const float* regb2 = (const float*)d_in[37];
  const float* regW3 = (const float*)d_in[38]; const float* regb3 = (const float*)d_in[39];
  const int* dei = (const int*)d_in[40];
  const int* ei0 = (const int*)d_in[42];
  const int* ei1 = (const int*)d_in[43];
  const int* cl0 = (const int*)d_in[44];
  const int* cl1 = (const int*)d_in[45];
  const int *dsrc = dei,       *ddst = dei + Ed;
  const int *src0 = ei0,       *dst0 = ei0 + Ec0;
  const int *src1 = ei1,       *dst1 = ei1 + Ec1;
  float* out = (float*)d_out;

  // ---- workspace layout ----
  char* base = (char*)d_ws; size_t off = 0;
  auto AL = [&](size_t bytes)->char* { char* p = base + off; off = (off + bytes + 255) & ~(size_t)255; return p; };
  float* h_cat   = (float*)AL((size_t)512*384*4);
  float* t1      = (float*)AL((size_t)512*384*4);
  float* t2      = (float*)AL((size_t)512*384*4);
  float* xd      = (float*)AL((size_t)512*384*4);
  float* cembh   = (float*)AL((size_t)512*1024*4);
  float* pooled1 = (float*)AL((size_t)nc1*16*4);
  float* pooled2 = (float*)AL((size_t)nc2*16*4);
  float* stats   = (float*)AL(256*4);
  int*   btot    = (int*)AL(512*4);
  char*  S       = base + off;   // shared scratch region, reused per phase
  if (ws_size < off + (size_t)56*1024*1024) return;  // need ~53MB scratch; bail cleanly

  dim3 b256(256);
  auto NB = [&](long total) { return dim3((unsigned)((total + 255) / 256)); };

  // ================= DRUG BRANCH =================
  {
    size_t so = 0;
    auto SA = [&](size_t bytes)->char* { char* p = S + so; so = (so + bytes + 255) & ~(size_t)255; return p; };
    float* reps = (float*)SA((size_t)nd*384*4);
    float* xin  = (float*)SA((size_t)nd*128*4);
    float* hbuf = (float*)SA((size_t)nd*128*4);
    float* W1p  = (float*)SA((size_t)96*128*4);
    int* degD = (int*)SA((size_t)nd*4);
    int* rowD = (int*)SA(((size_t)nd+1)*4);
    int* csrD = (int*)SA((size_t)Ed*4);

    // CSR by dst (built once, reused for 3 GIN layers)
    hipMemsetAsync(degD, 0, (size_t)nd*4, stream);
    k_deg<<<NB(Ed), b256, 0, stream>>>(ddst, Ed, 0, degD);
    k_scan_block<<<dim3(nd/1024), b256, 0, stream>>>(degD, nd, rowD, btot);
    k_scan_tot<<<1, 512, 0, stream>>>(btot, nd/1024);
    k_scan_add<<<NB(nd), b256, 0, stream>>>(rowD, btot, nd, Ed);
    hipMemsetAsync(degD, 0, (size_t)nd*4, stream);
    k_fill<<<NB(Ed), b256, 0, stream>>>(dsrc, ddst, Ed, 0, degD, rowD, csrD);

    // pad gin0_W1 (77x128) -> (96x128) so K is a multiple of 32
    k_pad<<<NB(96*128), b256, 0, stream>>>(gW1[0], 77, 128, W1p, 96, 128);

    const float* xsrc = drug_x; int xs = 77, F = 77, ds = 96;
    for (int L = 0; L < 3; ++L) {
      k_gin_gather<<<NB((long)nd*ds), b256, 0, stream>>>(rowD, csrD, xsrc, xs, F, xin, ds, nd);
      const float* W1 = (L == 0) ? W1p : gW1[L];
      int K1 = (L == 0) ? 96 : 128;
      k_gemm<1,0><<<dim3(2,320,1), b256, 0, stream>>>(xin, ds, W1, 128, gb1[L], hbuf, 128, K1);
      k_gemm<1,0><<<dim3(2,320,1), b256, 0, stream>>>(hbuf, 128, gW2[L], 128, gb2[L], xin, 128, 128);
      hipMemsetAsync(stats, 0, 256*4, stream);
      k_bn_stats<<<dim3(160), b256, 0, stream>>>(xin, nd, 128, stats);
      k_bn_apply<<<NB((long)nd*128), b256, 0, stream>>>(xin, 128, reps + L*128, 384,
                                                        stats, 1.f/nd, gg[L], gbe[L], nd*128, 128);
      xsrc = reps + L*128; xs = 384; F = 128; ds = 128;
    }
    k_drug_pool<<<dim3(512), dim3(384), 0, stream>>>(reps, xd);
    hipMemsetAsync(h_cat, 0, (size_t)512*384*4, stream);
    k_gemm<1,0><<<dim3(2,8,1), b256, 0, stream>>>(xd, 384, demb_W, 128, demb_b, h_cat, 384, 384);
  }

  // ================= CELL BRANCH: GAT layer 0 =================
  {
    size_t so = 0;
    auto SA = [&](size_t bytes)->char* { char* p = S + so; so = (so + bytes + 255) & ~(size_t)255; return p; };
    float* h0 = (float*)SA((size_t)nc0*16*4);
    float* ss = (float*)SA((size_t)nc0*4);
    float* sd = (float*)SA((size_t)nc0*4);
    int* deg = (int*)SA((size_t)nc0*4);
    int* row = (int*)SA(((size_t)nc0+1)*4);
    int* csr = (int*)SA((size_t)(Ec0+nc0)*4);

    k_gat_node<<<NB(nc0), b256, 0, stream>>>(cell_x, 3, gatW[0], gatAS[0], gatAD[0], h0, ss, sd, nc0);
    hipMemsetAsync(deg, 0, (size_t)nc0*4, stream);
    k_deg<<<NB((long)Ec0+nc0), b256, 0, stream>>>(dst0, Ec0, nc0, deg);
    k_scan_block<<<dim3(nc0/1024), b256, 0, stream>>>(deg, nc0, row, btot);
    k_scan_tot<<<1, 512, 0, stream>>>(btot, nc0/1024);
    k_scan_add<<<NB(nc0), b256, 0, stream>>>(row, btot, nc0, Ec0+nc0);
    hipMemsetAsync(deg, 0, (size_t)nc0*4, stream);
    k_fill<<<NB((long)Ec0+nc0), b256, 0, stream>>>(src0, dst0, Ec0, nc0, deg, row, csr);
    hipMemsetAsync(pooled1, 0, (size_t)nc1*16*4, stream);
    k_gat_gather_pool<<<NB(nc0), b256, 0, stream>>>(row, csr, ss, sd, h0, gatB[0], cl0, pooled1, nc0);
    hipMemsetAsync(stats, 0, 256*4, stream);
    k_bn_stats<<<dim3(256), b256, 0, stream>>>(pooled1, nc1, 16, stats);
    k_bn_apply<<<NB((long)nc1*16), b256, 0, stream>>>(pooled1, 16, pooled1, 16,
                                                      stats, 1.f/nc1, nullptr, nullptr, nc1*16, 16);
  }

  // ================= CELL BRANCH: GAT layer 1 =================
  {
    size_t so = 0;
    auto SA = [&](size_t bytes)->char* { char* p = S + so; so = (so + bytes + 255) & ~(size_t)255; return p; };
    float* h1 = (float*)SA((size_t)nc1*16*4);
    float* ss = (float*)SA((size_t)nc1*4);
    float* sd = (float*)SA((size_t)nc1*4);
    int* deg = (int*)SA((size_t)nc1*4);
    int* row = (int*)SA(((size_t)nc1+1)*4);
    int* csr = (int*)SA((size_t)(Ec1+nc1)*4);

    k_gat_node<<<NB(nc1), b256, 0, stream>>>(pooled1, 16, gatW[1], gatAS[1], gatAD[1], h1, ss, sd, nc1);
    hipMemsetAsync(deg, 0, (size_t)nc1*4, stream);
    k_deg<<<NB((long)Ec1+nc1), b256, 0, stream>>>(dst1, Ec1, nc1, deg);
    k_scan_block<<<dim3(nc1/1024), b256, 0, stream>>>(deg, nc1, row, btot);
    k_scan_tot<<<1, 512, 0, stream>>>(btot, nc1/1024);
    k_scan_add<<<NB(nc1), b256, 0, stream>>>(row, btot, nc1, Ec1+nc1);
    hipMemsetAsync(deg, 0, (size_t)nc1*4, stream);
    k_fill<<<NB((long)Ec1+nc1), b256, 0, stream>>>(src1, dst1, Ec1, nc1, deg, row, csr);
    hipMemsetAsync(pooled2, 0, (size_t)nc2*16*4, stream);
    k_gat_gather_pool<<<NB(nc1), b256, 0, stream>>>(row, csr, ss, sd, h1, gatB[1], cl1, pooled2, nc1);
    hipMemsetAsync(stats, 0, 256*4, stream);
    k_bn_stats<<<dim3(256), b256, 0, stream>>>(pooled2, nc2, 16, stats);
    k_bn_apply<<<NB((long)nc2*16), b256, 0, stream>>>(pooled2, 16, pooled2, 16,
                                                      stats, 1.f/nc2, nullptr, nullptr, nc2*16, 16);
  }

  // ================= cell embedding MLP =================
  // xc (512, 6400) @ cemb_W1 (6400,1024) -> relu ; split-K z=8 (Kchunk 800)
  hipMemsetAsync(cembh, 0, (size_t)512*1024*4, stream);
  k_gemm<0,1><<<dim3(16,8,8), b256, 0, stream>>>(pooled2, 6400, cembW1, 1024, nullptr, cembh, 1024, 800);
  k_bias_act<1><<<NB((long)512*1024), b256, 0, stream>>>(cembh, 1024, cembb1, 512, 1024);
  // (512,1024) @ (1024,256) -> relu, written into h_cat cols [128,384)
  k_gemm<0,1><<<dim3(4,8,8), b256, 0, stream>>>(cembh, 1024, cembW2, 256, nullptr, h_cat + 128, 384, 128);
  k_bias_act<1><<<NB((long)512*256), b256, 0, stream>>>(h_cat + 128, 384, cembb2, 512, 256);

  // ================= regressor =================
  hipMemsetAsync(t1, 0, (size_t)512*384*4, stream);
  k_gemm<0,1><<<dim3(6,8,4), b256, 0, stream>>>(h_cat, 384, regW1, 384, nullptr, t1, 384, 96);
  k_bias_act<2><<<NB((long)512*384), b256, 0, stream>>>(t1, 384, regb1, 512, 384);
  hipMemsetAsync(t2, 0, (size_t)512*384*4, stream);
  k_gemm<0,1><<<dim3(6,8,4), b256, 0, stream>>>(t1, 384, regW2, 384, nullptr, t2, 384, 96);
  k_bias_act<2><<<NB((long)512*384), b256, 0, stream>>>(t2, 384, regb2, 512, 384);
  k_gemv_out<<<dim3(512), dim3(64), 0, stream>>>(t2, regW3, regb3, out);
}

// Round 2
// 1324.911 us; speedup vs baseline: 1.1325x; 1.1325x over previous
//
#include <hip/hip_runtime.h>
#include <math.h>

// ===================== small utility kernels =====================

__global__ void k_pad(const float* __restrict__ src, int sr, int sc,
                      float* __restrict__ dst, int dr, int dc) {
  int t = blockIdx.x*blockDim.x + threadIdx.x;
  if (t >= dr*dc) return;
  int r = t/dc, c = t - r*dc;
  dst[t] = (r < sr && c < sc) ? src[r*sc + c] : 0.f;
}

__global__ void k_deg(const int* __restrict__ dst, int E, int nsl, int* __restrict__ deg) {
  int t = blockIdx.x*blockDim.x + threadIdx.x;
  if (t >= E + nsl) return;
  int d = (t < E) ? dst[t] : (t - E);
  atomicAdd(&deg[d], 1);
}

__global__ __launch_bounds__(256)
void k_scan_block(const int* __restrict__ deg, int n, int* __restrict__ out, int* __restrict__ btot) {
  __shared__ int sh[256];
  int tid = threadIdx.x;
  int base = blockIdx.x*1024 + tid*4;
  int v0 = (base+0<n)?deg[base+0]:0;
  int v1 = (base+1<n)?deg[base+1]:0;
  int v2 = (base+2<n)?deg[base+2]:0;
  int v3 = (base+3<n)?deg[base+3]:0;
  int s = v0+v1+v2+v3;
  sh[tid] = s; __syncthreads();
  for (int o = 1; o < 256; o <<= 1) {
    int t = (tid >= o) ? sh[tid-o] : 0;
    __syncthreads();
    sh[tid] += t;
    __syncthreads();
  }
  if (tid == 255) btot[blockIdx.x] = sh[255];
  int run = sh[tid] - s;
  if (base+0<n) { out[base+0]=run; run+=v0; }
  if (base+1<n) { out[base+1]=run; run+=v1; }
  if (base+2<n) { out[base+2]=run; run+=v2; }
  if (base+3<n) { out[base+3]=run; run+=v3; }
}

__global__ __launch_bounds__(512)
void k_scan_tot(int* __restrict__ btot, int nb) {
  __shared__ int sh[512];
  int tid = threadIdx.x;
  int v = (tid < nb) ? btot[tid] : 0;
  sh[tid] = v; __syncthreads();
  for (int o = 1; o < 512; o <<= 1) {
    int t = (tid >= o) ? sh[tid-o] : 0;
    __syncthreads();
    sh[tid] += t;
    __syncthreads();
  }
  if (tid < nb) btot[tid] = sh[tid] - v;
}

__global__ void k_scan_add(int* __restrict__ rowptr, const int* __restrict__ btot, int n, int total) {
  int t = blockIdx.x*blockDim.x + threadIdx.x;
  if (t < n) rowptr[t] += btot[t >> 10];
  if (t == 0) rowptr[n] = total;
}

__global__ void k_fill(const int* __restrict__ src, const int* __restrict__ dst, int E, int nsl,
                       int* __restrict__ cursor, const int* __restrict__ rowptr, int* __restrict__ csr) {
  int t = blockIdx.x*blockDim.x + threadIdx.x;
  if (t >= E + nsl) return;
  int s, d;
  if (t < E) { s = src[t]; d = dst[t]; } else { s = t - E; d = s; }
  int slot = rowptr[d] + atomicAdd(&cursor[d], 1);
  csr[slot] = s;
}

// ===================== GIN (drug) =====================
__global__ void k_gin_gather(const int* __restrict__ rowptr, const int* __restrict__ csr,
                             const float* __restrict__ x, int xs, int F,
                             float* __restrict__ xin, int ds, int n) {
  int t = blockIdx.x*blockDim.x + threadIdx.x;
  if (t >= n*ds) return;
  int d = t/ds, f = t - d*ds;
  if (f >= F) { xin[t] = 0.f; return; }
  float acc = x[(size_t)d*xs + f];
  int e1 = rowptr[d+1];
  for (int j = rowptr[d]; j < e1; ++j) acc += x[(size_t)csr[j]*xs + f];
  xin[t] = acc;
}

__global__ __launch_bounds__(384)
void k_drug_pool(const float* __restrict__ reps, float* __restrict__ xd) {
  int b = blockIdx.x, c = threadIdx.x;
  float m = -3.0e38f;
  const float* p = reps + (size_t)b*40*384 + c;
  for (int i = 0; i < 40; ++i) m = fmaxf(m, p[(size_t)i*384]);
  xd[(size_t)b*384 + c] = m;
}

// ===================== GEMM (f32, tiled 64x64, optional split-K atomics) =====================
template<int ACT, int ATOMIC>   // ACT: 0 none, 1 relu, 2 elu (non-atomic path only)
__global__ __launch_bounds__(256)
void k_gemm(const float* __restrict__ A, int lda,
            const float* __restrict__ B, int ldb,
            const float* __restrict__ bias,
            float* __restrict__ C, int ldc, int Kchunk) {
  __shared__ __align__(16) float As[32][68];   // As[k][m]
  __shared__ __align__(16) float Bs[32][68];   // Bs[k][n]
  const int tid = threadIdx.x;
  const int tx = tid & 15, ty = tid >> 4;
  const int row0 = blockIdx.y << 6, col0 = blockIdx.x << 6;
  const int kb = blockIdx.z * Kchunk;
  float acc[4][4] = {{0.f}};
  for (int k0 = 0; k0 < Kchunk; k0 += 32) {
#pragma unroll
    for (int i = 0; i < 2; ++i) {
      int idx = tid + (i << 8);
      int r = idx >> 3, c = (idx & 7) << 2;
      float4 v = *(const float4*)(A + (size_t)(row0 + r)*lda + (kb + k0 + c));
      As[c+0][r]=v.x; As[c+1][r]=v.y; As[c+2][r]=v.z; As[c+3][r]=v.w;
    }
#pragma unroll
    for (int i = 0; i < 2; ++i) {
      int idx = tid + (i << 8);
      int r = idx >> 4, c = (idx & 15) << 2;
      *(float4*)&Bs[r][c] = *(const float4*)(B + (size_t)(kb + k0 + r)*ldb + (col0 + c));
    }
    __syncthreads();
#pragma unroll
    for (int kk = 0; kk < 32; ++kk) {
      float4 av = *(const float4*)&As[kk][ty << 2];
      float4 bv = *(const float4*)&Bs[kk][tx << 2];
      acc[0][0]=fmaf(av.x,bv.x,acc[0][0]); acc[0][1]=fmaf(av.x,bv.y,acc[0][1]);
      acc[0][2]=fmaf(av.x,bv.z,acc[0][2]); acc[0][3]=fmaf(av.x,bv.w,acc[0][3]);
      acc[1][0]=fmaf(av.y,bv.x,acc[1][0]); acc[1][1]=fmaf(av.y,bv.y,acc[1][1]);
      acc[1][2]=fmaf(av.y,bv.z,acc[1][2]); acc[1][3]=fmaf(av.y,bv.w,acc[1][3]);
      acc[2][0]=fmaf(av.z,bv.x,acc[2][0]); acc[2][1]=fmaf(av.z,bv.y,acc[2][1]);
      acc[2][2]=fmaf(av.z,bv.z,acc[2][2]); acc[2][3]=fmaf(av.z,bv.w,acc[2][3]);
      acc[3][0]=fmaf(av.w,bv.x,acc[3][0]); acc[3][1]=fmaf(av.w,bv.y,acc[3][1]);
      acc[3][2]=fmaf(av.w,bv.z,acc[3][2]); acc[3][3]=fmaf(av.w,bv.w,acc[3][3]);
    }
    __syncthreads();
  }
  if (ATOMIC) {
#pragma unroll
    for (int i = 0; i < 4; ++i) {
      int r = row0 + (ty<<2) + i, c = col0 + (tx<<2);
#pragma unroll
      for (int j = 0; j < 4; ++j) atomicAdd(&C[(size_t)r*ldc + c + j], acc[i][j]);
    }
  } else {
#pragma unroll
    for (int i = 0; i < 4; ++i) {
      int r = row0 + (ty<<2) + i, c = col0 + (tx<<2);
      float4 v = make_float4(acc[i][0], acc[i][1], acc[i][2], acc[i][3]);
      if (bias) { v.x += bias[c]; v.y += bias[c+1]; v.z += bias[c+2]; v.w += bias[c+3]; }
      if (ACT == 1) { v.x=fmaxf(v.x,0.f); v.y=fmaxf(v.y,0.f); v.z=fmaxf(v.z,0.f); v.w=fmaxf(v.w,0.f); }
      else if (ACT == 2) {
        v.x = v.x>0.f?v.x:expm1f(v.x); v.y = v.y>0.f?v.y:expm1f(v.y);
        v.z = v.z>0.f?v.z:expm1f(v.z); v.w = v.w>0.f?v.w:expm1f(v.w);
      }
      *(float4*)(C + (size_t)r*ldc + c) = v;
    }
  }
}

template<int ACT>
__global__ void k_bias_act(float* __restrict__ C, int ldc, const float* __restrict__ bias, int M, int N) {
  int t = blockIdx.x*blockDim.x + threadIdx.x;
  if (t >= M*N) return;
  int r = t / N, c = t - r*N;
  float v = C[(size_t)r*ldc + c] + bias[c];
  if (ACT == 1) v = fmaxf(v, 0.f);
  else if (ACT == 2) v = v > 0.f ? v : expm1f(v);
  C[(size_t)r*ldc + c] = v;
}

// ===================== BatchNorm =====================
__global__ __launch_bounds__(256)
void k_bn_stats(const float* __restrict__ x, int rows, int cols, float* __restrict__ acc) {
  __shared__ float sh[256], sh2[256];
  int tid = threadIdx.x;
  int nth = gridDim.x * 256;
  int t = blockIdx.x*256 + tid;
  int c = t % cols;
  int r0 = t / cols;
  int rstep = nth / cols;
  float s = 0.f, s2 = 0.f;
  for (int r = r0; r < rows; r += rstep) {
    float v = x[(size_t)r*cols + c];
    s += v; s2 = fmaf(v, v, s2);
  }
  sh[tid] = s; sh2[tid] = s2; __syncthreads();
  for (int o = 128; o >= cols; o >>= 1) {
    if (tid < o) { sh[tid] += sh[tid+o]; sh2[tid] += sh2[tid+o]; }
    __syncthreads();
  }
  if (tid < cols) { atomicAdd(&acc[tid], sh[tid]); atomicAdd(&acc[cols+tid], sh2[tid]); }
}

__global__ void k_bn_apply(const float* __restrict__ x, int xs,
                           float* __restrict__ y, int ys,
                           const float* __restrict__ acc, float invn,
                           const float* __restrict__ g, const float* __restrict__ be,
                           int total, int cols) {
  int t = blockIdx.x*blockDim.x + threadIdx.x;
  if (t >= total) return;
  int c = t % cols;
  int r = t / cols;
  float mu = acc[c] * invn;
  float var = fmaxf(acc[cols+c]*invn - mu*mu, 0.f);
  float rstd = rsqrtf(var + 1e-5f);
  float v = (x[(size_t)r*xs + c] - mu) * rstd;
  if (g) v = fmaf(v, g[c], be[c]);
  y[(size_t)r*ys + c] = v;
}

// ===================== GAT =====================
__global__ void k_gat_node(const float* __restrict__ x, int K,
                           const float* __restrict__ W,
                           const float* __restrict__ as_, const float* __restrict__ ad_,
                           float* __restrict__ h, float* __restrict__ ssrc, float* __restrict__ sdst,
                           int n) {
  int i = blockIdx.x*blockDim.x + threadIdx.x;
  if (i >= n) return;
  float hv[16];
#pragma unroll
  for (int k = 0; k < 16; ++k) hv[k] = 0.f;
  for (int j = 0; j < K; ++j) {
    float xv = x[(size_t)i*K + j];
#pragma unroll
    for (int k = 0; k < 16; ++k) hv[k] = fmaf(xv, W[j*16 + k], hv[k]);
  }
  float s1 = 0.f, s2 = 0.f;
#pragma unroll
  for (int k = 0; k < 16; ++k) { s1 = fmaf(hv[k], as_[k], s1); s2 = fmaf(hv[k], ad_[k], s2); }
  float4* hp = (float4*)(h + (size_t)i*16);
  hp[0] = make_float4(hv[0],hv[1],hv[2],hv[3]);
  hp[1] = make_float4(hv[4],hv[5],hv[6],hv[7]);
  hp[2] = make_float4(hv[8],hv[9],hv[10],hv[11]);
  hp[3] = make_float4(hv[12],hv[13],hv[14],hv[15]);
  ssrc[i] = s1; sdst[i] = s2;
}

// 16 lanes per destination node: lane k owns feature k. h-row reads are one
// coalesced 64B transaction per group; csr/ssrc loads are broadcast; the
// logit/exp is recomputed per-lane (VALU was 97% idle). 16x the TLP of the
// one-thread-per-node version, which was latency-bound (VALUBusy 2.5%).
__global__ __launch_bounds__(256)
void k_gat_gather_pool16(const int* __restrict__ rowptr, const int* __restrict__ csr,
                         const float* __restrict__ ssrc, const float* __restrict__ sdst,
                         const float* __restrict__ h, const float* __restrict__ bias,
                         const int* __restrict__ cluster,
                         float* __restrict__ pooled, int n) {
  int g = (blockIdx.x*blockDim.x + threadIdx.x) >> 4;
  int lane = threadIdx.x & 15;
  if (g >= n) return;
  float sd = sdst[g];
  float acc = 0.f, sum = 0.f;
  int e1 = rowptr[g+1];
  for (int j = rowptr[g]; j < e1; ++j) {
    int s = csr[j];
    float l = ssrc[s] + sd;
    l = (l > 0.f) ? l : 0.2f*l;
    float e = expf(l);                 // no max-subtraction: ratios identical, f32-safe
    sum += e;
    acc = fmaf(e, h[(size_t)s*16 + lane], acc);
  }
  float v = fmaf(acc, 1.f/sum, bias[lane]);
  v = fmaxf(v, 0.f);
  atomicMax((int*)(pooled + (size_t)cluster[g]*16 + lane), __float_as_int(v));
}

// ===================== final GEMV =====================
__global__ __launch_bounds__(64)
void k_gemv_out(const float* __restrict__ A, const float* __restrict__ w,
                const float* __restrict__ b, float* __restrict__ out) {
  int r = blockIdx.x, l = threadIdx.x;
  float s = 0.f;
  for (int k = l; k < 384; k += 64) s = fmaf(A[(size_t)r*384 + k], w[k], s);
#pragma unroll
  for (int o = 32; o > 0; o >>= 1) s += __shfl_down(s, o);
  if (l == 0) out[r] = s + b[0];
}

// ===================== host orchestration =====================
extern "C" void kernel_launch(void* const* d_in, const int* in_sizes, int n_in,
                              void* d_out, int out_size, void* d_ws, size_t ws_size,
                              hipStream_t stream) {
  (void)n_in; (void)out_size;
  const int B = 512, N0 = 706, C1v = 512, C2v = 400;
  const int nd  = B*40;
  const int nc0 = B*N0;
  const int nc1 = B*C1v;
  const int nc2 = B*C2v;
  const int Ed  = in_sizes[40]/2;
  const int Ec0 = in_sizes[42]/2;
  const int Ec1 = in_sizes[43]/2;

  const float* drug_x = (const float*)d_in[0];
  const float* cell_x = (const float*)d_in[1];
  const float* gW1[3] = {(const float*)d_in[2],(const float*)d_in[8],(const float*)d_in[14]};
  const float* gb1[3] = {(const float*)d_in[3],(const float*)d_in[9],(const float*)d_in[15]};
  const float* gW2[3] = {(const float*)d_in[4],(const float*)d_in[10],(const float*)d_in[16]};
  const float* gb2[3] = {(const float*)d_in[5],(const float*)d_in[11],(const float*)d_in[17]};
  const float* gg [3] = {(const float*)d_in[6],(const float*)d_in[12],(const float*)d_in[18]};
  const float* gbe[3] = {(const float*)d_in[7],(const float*)d_in[13],(const float*)d_in[19]};
  const float* demb_W = (const float*)d_in[20]; const float* demb_b = (const float*)d_in[21];
  const float* gatW[2]  = {(const float*)d_in[22],(const float*)d_in[26]};
  const float* gatAS[2] = {(const float*)d_in[23],(const float*)d_in[27]};
  const float* gatAD[2] = {(const float*)d_in[24],(const float*)d_in[28]};
  const float* gatB[2]  = {(const float*)d_in[25],(const float*)d_in[29]};
  const float* cembW1 = (const float*)d_in[30]; const float* cembb1 = (const float*)d_in[31];
  const float* cembW2 = (const float*)d_in[32]; const float* cembb2 = (const float*)d_in[33];
  const float* regW1 = (const float*)d_in[34]; const float* regb1 = (const float*)d_in[35];
  const float* regW2 = (const float*)d_in[36]; const float* regb2 = (const float*)d_in[37];
  const float* regW3 = (const float*)d_in[38]; const float* regb3 = (const float*)d_in[39];
  const int* dei = (const int*)d_in[40];
  const int* ei0 = (const int*)d_in[42];
  const int* ei1 = (const int*)d_in[43];
  const int* cl0 = (const int*)d_in[44];
  const int* cl1 = (const int*)d_in[45];
  const int *dsrc = dei,       *ddst = dei + Ed;
  const int *src0 = ei0,       *dst0 = ei0 + Ec0;
  const int *src1 = ei1,       *dst1 = ei1 + Ec1;
  float* out = (float*)d_out;

  // ---- workspace layout ----
  char* base = (char*)d_ws; size_t off = 0;
  auto AL = [&](size_t bytes)->char* { char* p = base + off; off = (off + bytes + 255) & ~(size_t)255; return p; };
  float* h_cat   = (float*)AL((size_t)512*384*4);
  float* t1      = (float*)AL((size_t)512*384*4);
  float* t2      = (float*)AL((size_t)512*384*4);
  float* xd      = (float*)AL((size_t)512*384*4);
  float* cembh   = (float*)AL((size_t)512*1024*4);
  float* pooled1 = (float*)AL((size_t)nc1*16*4);
  float* pooled2 = (float*)AL((size_t)nc2*16*4);
  float* stats   = (float*)AL(256*4);
  int*   btot    = (int*)AL(512*4);
  char*  S       = base + off;
  if (ws_size < off + (size_t)56*1024*1024) return;

  dim3 b256(256);
  auto NB = [&](long total) { return dim3((unsigned)((total + 255) / 256)); };

  // ================= DRUG BRANCH =================
  {
    size_t so = 0;
    auto SA = [&](size_t bytes)->char* { char* p = S + so; so = (so + bytes + 255) & ~(size_t)255; return p; };
    float* reps = (float*)SA((size_t)nd*384*4);
    float* xin  = (float*)SA((size_t)nd*128*4);
    float* hbuf = (float*)SA((size_t)nd*128*4);
    float* W1p  = (float*)SA((size_t)96*128*4);
    int* degD = (int*)SA((size_t)nd*4);
    int* rowD = (int*)SA(((size_t)nd+1)*4);
    int* csrD = (int*)SA((size_t)Ed*4);

    hipMemsetAsync(degD, 0, (size_t)nd*4, stream);
    k_deg<<<NB(Ed), b256, 0, stream>>>(ddst, Ed, 0, degD);
    k_scan_block<<<dim3(nd/1024), b256, 0, stream>>>(degD, nd, rowD, btot);
    k_scan_tot<<<1, 512, 0, stream>>>(btot, nd/1024);
    k_scan_add<<<NB(nd), b256, 0, stream>>>(rowD, btot, nd, Ed);
    hipMemsetAsync(degD, 0, (size_t)nd*4, stream);
    k_fill<<<NB(Ed), b256, 0, stream>>>(dsrc, ddst, Ed, 0, degD, rowD, csrD);

    k_pad<<<NB(96*128), b256, 0, stream>>>(gW1[0], 77, 128, W1p, 96, 128);

    const float* xsrc = drug_x; int xs = 77, F = 77, ds = 96;
    for (int L = 0; L < 3; ++L) {
      k_gin_gather<<<NB((long)nd*ds), b256, 0, stream>>>(rowD, csrD, xsrc, xs, F, xin, ds, nd);
      const float* W1 = (L == 0) ? W1p : gW1[L];
      int K1 = (L == 0) ? 96 : 128;
      k_gemm<1,0><<<dim3(2,320,1), b256, 0, stream>>>(xin, ds, W1, 128, gb1[L], hbuf, 128, K1);
      k_gemm<1,0><<<dim3(2,320,1), b256, 0, stream>>>(hbuf, 128, gW2[L], 128, gb2[L], xin, 128, 128);
      hipMemsetAsync(stats, 0, 256*4, stream);
      k_bn_stats<<<dim3(160), b256, 0, stream>>>(xin, nd, 128, stats);
      k_bn_apply<<<NB((long)nd*128), b256, 0, stream>>>(xin, 128, reps + L*128, 384,
                                                        stats, 1.f/nd, gg[L], gbe[L], nd*128, 128);
      xsrc = reps + L*128; xs = 384; F = 128; ds = 128;
    }
    k_drug_pool<<<dim3(512), dim3(384), 0, stream>>>(reps, xd);
    hipMemsetAsync(h_cat, 0, (size_t)512*384*4, stream);
    k_gemm<1,0><<<dim3(2,8,1), b256, 0, stream>>>(xd, 384, demb_W, 128, demb_b, h_cat, 384, 384);
  }

  // ================= CELL BRANCH: GAT layer 0 =================
  {
    size_t so = 0;
    auto SA = [&](size_t bytes)->char* { char* p = S + so; so = (so + bytes + 255) & ~(size_t)255; return p; };
    float* h0 = (float*)SA((size_t)nc0*16*4);
    float* ss = (float*)SA((size_t)nc0*4);
    float* sd = (float*)SA((size_t)nc0*4);
    int* deg = (int*)SA((size_t)nc0*4);
    int* row = (int*)SA(((size_t)nc0+1)*4);
    int* csr = (int*)SA((size_t)(Ec0+nc0)*4);

    k_gat_node<<<NB(nc0), b256, 0, stream>>>(cell_x, 3, gatW[0], gatAS[0], gatAD[0], h0, ss, sd, nc0);
    hipMemsetAsync(deg, 0, (size_t)nc0*4, stream);
    k_deg<<<NB((long)Ec0+nc0), b256, 0, stream>>>(dst0, Ec0, nc0, deg);
    k_scan_block<<<dim3(nc0/1024), b256, 0, stream>>>(deg, nc0, row, btot);
    k_scan_tot<<<1, 512, 0, stream>>>(btot, nc0/1024);
    k_scan_add<<<NB(nc0), b256, 0, stream>>>(row, btot, nc0, Ec0+nc0);
    hipMemsetAsync(deg, 0, (size_t)nc0*4, stream);
    k_fill<<<NB((long)Ec0+nc0), b256, 0, stream>>>(src0, dst0, Ec0, nc0, deg, row, csr);
    hipMemsetAsync(pooled1, 0, (size_t)nc1*16*4, stream);
    k_gat_gather_pool16<<<NB((long)nc0*16), b256, 0, stream>>>(row, csr, ss, sd, h0, gatB[0], cl0, pooled1, nc0);
    hipMemsetAsync(stats, 0, 256*4, stream);
    k_bn_stats<<<dim3(256), b256, 0, stream>>>(pooled1, nc1, 16, stats);
    k_bn_apply<<<NB((long)nc1*16), b256, 0, stream>>>(pooled1, 16, pooled1, 16,
                                                      stats, 1.f/nc1, nullptr, nullptr, nc1*16, 16);
  }

  // ================= CELL BRANCH: GAT layer 1 =================
  {
    size_t so = 0;
    auto SA = [&](size_t bytes)->char* { char* p = S + so; so = (so + bytes + 255) & ~(size_t)255; return p; };
    float* h1 = (float*)SA((size_t)nc1*16*4);
    float* ss = (float*)SA((size_t)nc1*4);
    float* sd = (float*)SA((size_t)nc1*4);
    int* deg = (int*)SA((size_t)nc1*4);
    int* row = (int*)SA(((size_t)nc1+1)*4);
    int* csr = (int*)SA((size_t)(Ec1+nc1)*4);

    k_gat_node<<<NB(nc1), b256, 0, stream>>>(pooled1, 16, gatW[1], gatAS[1], gatAD[1], h1, ss, sd, nc1);
    hipMemsetAsync(deg, 0, (size_t)nc1*4, stream);
    k_deg<<<NB((long)Ec1+nc1), b256, 0, stream>>>(dst1, Ec1, nc1, deg);
    k_scan_block<<<dim3(nc1/1024), b256, 0, stream>>>(deg, nc1, row, btot);
    k_scan_tot<<<1, 512, 0, stream>>>(btot, nc1/1024);
    k_scan_add<<<NB(nc1), b256, 0, stream>>>(row, btot, nc1, Ec1+nc1);
    hipMemsetAsync(deg, 0, (size_t)nc1*4, stream);
    k_fill<<<NB((long)Ec1+nc1), b256, 0, stream>>>(src1, dst1, Ec1, nc1, deg, row, csr);
    hipMemsetAsync(pooled2, 0, (size_t)nc2*16*4, stream);
    k_gat_gather_pool16<<<NB((long)nc1*16), b256, 0, stream>>>(row, csr, ss, sd, h1, gatB[1], cl1, pooled2, nc1);
    hipMemsetAsync(stats, 0, 256*4, stream);
    k_bn_stats<<<dim3(256), b256, 0, stream>>>(pooled2, nc2, 16, stats);
    k_bn_apply<<<NB((long)nc2*16), b256, 0, stream>>>(pooled2, 16, pooled2, 16,
                                                      stats, 1.f/nc2, nullptr, nullptr, nc2*16, 16);
  }

  // ================= cell embedding MLP =================
  hipMemsetAsync(cembh, 0, (size_t)512*1024*4, stream);
  k_gemm<0,1><<<dim3(16,8,8), b256, 0, stream>>>(pooled2, 6400, cembW1, 1024, nullptr, cembh, 1024, 800);
  k_bias_act<1><<<NB((long)512*1024), b256, 0, stream>>>(cembh, 1024, cembb1, 512, 1024);
  k_gemm<0,1><<<dim3(4,8,8), b256, 0, stream>>>(cembh, 1024, cembW2, 256, nullptr, h_cat + 128, 384, 128);
  k_bias_act<1><<<NB((long)512*256), b256, 0, stream>>>(h_cat + 128, 384, cembb2, 512, 256);

  // ================= regressor =================
  hipMemsetAsync(t1, 0, (size_t)512*384*4, stream);
  k_gemm<0,1><<<dim3(6,8,4), b256, 0, stream>>>(h_cat, 384, regW1, 384, nullptr, t1, 384, 96);
  k_bias_act<2><<<NB((long)512*384), b256, 0, stream>>>(t1, 384, regb1, 512, 384);
  hipMemsetAsync(t2, 0, (size_t)512*384*4, stream);
  k_gemm<0,1><<<dim3(6,8,4), b256, 0, stream>>>(t1, 384, regW2, 384, nullptr, t2, 384, 96);
  k_bias_act<2><<<NB((long)512*384), b256, 0, stream>>>(t2, 384, regb2, 512, 384);
  k_gemv_out<<<dim3(512), dim3(64), 0, stream>>>(t2, regW3, regb3, out);
}

// Round 3
// 1186.646 us; speedup vs baseline: 1.2645x; 1.1165x over previous
//
#include <hip/hip_runtime.h>
#include <math.h>

// ===================== small utility kernels =====================

__global__ void k_pad(const float* __restrict__ src, int sr, int sc,
                      float* __restrict__ dst, int dr, int dc) {
  int t = blockIdx.x*blockDim.x + threadIdx.x;
  if (t >= dr*dc) return;
  int r = t/dc, c = t - r*dc;
  dst[t] = (r < sr && c < sc) ? src[r*sc + c] : 0.f;
}

__global__ void k_deg(const int* __restrict__ dst, int E, int nsl, int* __restrict__ deg) {
  int t = blockIdx.x*blockDim.x + threadIdx.x;
  if (t >= E + nsl) return;
  int d = (t < E) ? dst[t] : (t - E);
  atomicAdd(&deg[d], 1);
}

__global__ __launch_bounds__(256)
void k_scan_block(const int* __restrict__ deg, int n, int* __restrict__ out, int* __restrict__ btot) {
  __shared__ int sh[256];
  int tid = threadIdx.x;
  int base = blockIdx.x*1024 + tid*4;
  int v0 = (base+0<n)?deg[base+0]:0;
  int v1 = (base+1<n)?deg[base+1]:0;
  int v2 = (base+2<n)?deg[base+2]:0;
  int v3 = (base+3<n)?deg[base+3]:0;
  int s = v0+v1+v2+v3;
  sh[tid] = s; __syncthreads();
  for (int o = 1; o < 256; o <<= 1) {
    int t = (tid >= o) ? sh[tid-o] : 0;
    __syncthreads();
    sh[tid] += t;
    __syncthreads();
  }
  if (tid == 255) btot[blockIdx.x] = sh[255];
  int run = sh[tid] - s;
  if (base+0<n) { out[base+0]=run; run+=v0; }
  if (base+1<n) { out[base+1]=run; run+=v1; }
  if (base+2<n) { out[base+2]=run; run+=v2; }
  if (base+3<n) { out[base+3]=run; run+=v3; }
}

__global__ __launch_bounds__(512)
void k_scan_tot(int* __restrict__ btot, int nb) {
  __shared__ int sh[512];
  int tid = threadIdx.x;
  int v = (tid < nb) ? btot[tid] : 0;
  sh[tid] = v; __syncthreads();
  for (int o = 1; o < 512; o <<= 1) {
    int t = (tid >= o) ? sh[tid-o] : 0;
    __syncthreads();
    sh[tid] += t;
    __syncthreads();
  }
  if (tid < nb) btot[tid] = sh[tid] - v;
}

__global__ void k_scan_add(int* __restrict__ rowptr, const int* __restrict__ btot, int n, int total) {
  int t = blockIdx.x*blockDim.x + threadIdx.x;
  if (t < n) rowptr[t] += btot[t >> 10];
  if (t == 0) rowptr[n] = total;
}

__global__ void k_fill(const int* __restrict__ src, const int* __restrict__ dst, int E, int nsl,
                       int* __restrict__ cursor, const int* __restrict__ rowptr, int* __restrict__ csr) {
  int t = blockIdx.x*blockDim.x + threadIdx.x;
  if (t >= E + nsl) return;
  int s, d;
  if (t < E) { s = src[t]; d = dst[t]; } else { s = t - E; d = s; }
  int slot = rowptr[d] + atomicAdd(&cursor[d], 1);
  csr[slot] = s;
}

// CSR fill fused with edge-parallel exp(leaky(ssrc+sdst)): writes ew[slot].
__global__ void k_fill_gat(const int* __restrict__ src, const int* __restrict__ dst, int E, int nsl,
                           int* __restrict__ cursor, const int* __restrict__ rowptr,
                           const float* __restrict__ ssrc, const float* __restrict__ sdst,
                           int* __restrict__ csr, float* __restrict__ ew) {
  int t = blockIdx.x*blockDim.x + threadIdx.x;
  if (t >= E + nsl) return;
  int s, d;
  if (t < E) { s = src[t]; d = dst[t]; } else { s = t - E; d = s; }
  int slot = rowptr[d] + atomicAdd(&cursor[d], 1);
  float l = ssrc[s] + sdst[d];
  l = (l > 0.f) ? l : 0.2f*l;
  csr[slot] = s;
  ew[slot] = expf(l);   // no max-subtraction: alpha ratios identical, f32-safe
}

// ===================== GIN (drug) =====================
__global__ void k_gin_gather(const int* __restrict__ rowptr, const int* __restrict__ csr,
                             const float* __restrict__ x, int xs, int F,
                             float* __restrict__ xin, int ds, int n) {
  int t = blockIdx.x*blockDim.x + threadIdx.x;
  if (t >= n*ds) return;
  int d = t/ds, f = t - d*ds;
  if (f >= F) { xin[t] = 0.f; return; }
  float acc = x[(size_t)d*xs + f];
  int e1 = rowptr[d+1];
  for (int j = rowptr[d]; j < e1; ++j) acc += x[(size_t)csr[j]*xs + f];
  xin[t] = acc;
}

__global__ __launch_bounds__(384)
void k_drug_pool(const float* __restrict__ reps, float* __restrict__ xd) {
  int b = blockIdx.x, c = threadIdx.x;
  float m = -3.0e38f;
  const float* p = reps + (size_t)b*40*384 + c;
  for (int i = 0; i < 40; ++i) m = fmaxf(m, p[(size_t)i*384]);
  xd[(size_t)b*384 + c] = m;
}

// ===================== GEMM (f32, tiled 64x64, optional split-K atomics) =====================
template<int ACT, int ATOMIC>   // ACT: 0 none, 1 relu, 2 elu (non-atomic path only)
__global__ __launch_bounds__(256)
void k_gemm(const float* __restrict__ A, int lda,
            const float* __restrict__ B, int ldb,
            const float* __restrict__ bias,
            float* __restrict__ C, int ldc, int Kchunk) {
  __shared__ __align__(16) float As[32][68];
  __shared__ __align__(16) float Bs[32][68];
  const int tid = threadIdx.x;
  const int tx = tid & 15, ty = tid >> 4;
  const int row0 = blockIdx.y << 6, col0 = blockIdx.x << 6;
  const int kb = blockIdx.z * Kchunk;
  float acc[4][4] = {{0.f}};
  for (int k0 = 0; k0 < Kchunk; k0 += 32) {
#pragma unroll
    for (int i = 0; i < 2; ++i) {
      int idx = tid + (i << 8);
      int r = idx >> 3, c = (idx & 7) << 2;
      float4 v = *(const float4*)(A + (size_t)(row0 + r)*lda + (kb + k0 + c));
      As[c+0][r]=v.x; As[c+1][r]=v.y; As[c+2][r]=v.z; As[c+3][r]=v.w;
    }
#pragma unroll
    for (int i = 0; i < 2; ++i) {
      int idx = tid + (i << 8);
      int r = idx >> 4, c = (idx & 15) << 2;
      *(float4*)&Bs[r][c] = *(const float4*)(B + (size_t)(kb + k0 + r)*ldb + (col0 + c));
    }
    __syncthreads();
#pragma unroll
    for (int kk = 0; kk < 32; ++kk) {
      float4 av = *(const float4*)&As[kk][ty << 2];
      float4 bv = *(const float4*)&Bs[kk][tx << 2];
      acc[0][0]=fmaf(av.x,bv.x,acc[0][0]); acc[0][1]=fmaf(av.x,bv.y,acc[0][1]);
      acc[0][2]=fmaf(av.x,bv.z,acc[0][2]); acc[0][3]=fmaf(av.x,bv.w,acc[0][3]);
      acc[1][0]=fmaf(av.y,bv.x,acc[1][0]); acc[1][1]=fmaf(av.y,bv.y,acc[1][1]);
      acc[1][2]=fmaf(av.y,bv.z,acc[1][2]); acc[1][3]=fmaf(av.y,bv.w,acc[1][3]);
      acc[2][0]=fmaf(av.z,bv.x,acc[2][0]); acc[2][1]=fmaf(av.z,bv.y,acc[2][1]);
      acc[2][2]=fmaf(av.z,bv.z,acc[2][2]); acc[2][3]=fmaf(av.z,bv.w,acc[2][3]);
      acc[3][0]=fmaf(av.w,bv.x,acc[3][0]); acc[3][1]=fmaf(av.w,bv.y,acc[3][1]);
      acc[3][2]=fmaf(av.w,bv.z,acc[3][2]); acc[3][3]=fmaf(av.w,bv.w,acc[3][3]);
    }
    __syncthreads();
  }
  if (ATOMIC) {
#pragma unroll
    for (int i = 0; i < 4; ++i) {
      int r = row0 + (ty<<2) + i, c = col0 + (tx<<2);
#pragma unroll
      for (int j = 0; j < 4; ++j) atomicAdd(&C[(size_t)r*ldc + c + j], acc[i][j]);
    }
  } else {
#pragma unroll
    for (int i = 0; i < 4; ++i) {
      int r = row0 + (ty<<2) + i, c = col0 + (tx<<2);
      float4 v = make_float4(acc[i][0], acc[i][1], acc[i][2], acc[i][3]);
      if (bias) { v.x += bias[c]; v.y += bias[c+1]; v.z += bias[c+2]; v.w += bias[c+3]; }
      if (ACT == 1) { v.x=fmaxf(v.x,0.f); v.y=fmaxf(v.y,0.f); v.z=fmaxf(v.z,0.f); v.w=fmaxf(v.w,0.f); }
      else if (ACT == 2) {
        v.x = v.x>0.f?v.x:expm1f(v.x); v.y = v.y>0.f?v.y:expm1f(v.y);
        v.z = v.z>0.f?v.z:expm1f(v.z); v.w = v.w>0.f?v.w:expm1f(v.w);
      }
      *(float4*)(C + (size_t)r*ldc + c) = v;
    }
  }
}

template<int ACT>
__global__ void k_bias_act(float* __restrict__ C, int ldc, const float* __restrict__ bias, int M, int N) {
  int t = blockIdx.x*blockDim.x + threadIdx.x;
  if (t >= M*N) return;
  int r = t / N, c = t - r*N;
  float v = C[(size_t)r*ldc + c] + bias[c];
  if (ACT == 1) v = fmaxf(v, 0.f);
  else if (ACT == 2) v = v > 0.f ? v : expm1f(v);
  C[(size_t)r*ldc + c] = v;
}

// ===================== BatchNorm =====================
__global__ __launch_bounds__(256)
void k_bn_stats(const float* __restrict__ x, int rows, int cols, float* __restrict__ acc) {
  __shared__ float sh[256], sh2[256];
  int tid = threadIdx.x;
  int nth = gridDim.x * 256;
  int t = blockIdx.x*256 + tid;
  int c = t % cols;
  int r0 = t / cols;
  int rstep = nth / cols;
  float s = 0.f, s2 = 0.f;
  for (int r = r0; r < rows; r += rstep) {
    float v = x[(size_t)r*cols + c];
    s += v; s2 = fmaf(v, v, s2);
  }
  sh[tid] = s; sh2[tid] = s2; __syncthreads();
  for (int o = 128; o >= cols; o >>= 1) {
    if (tid < o) { sh[tid] += sh[tid+o]; sh2[tid] += sh2[tid+o]; }
    __syncthreads();
  }
  if (tid < cols) { atomicAdd(&acc[tid], sh[tid]); atomicAdd(&acc[cols+tid], sh2[tid]); }
}

__global__ void k_bn_apply(const float* __restrict__ x, int xs,
                           float* __restrict__ y, int ys,
                           const float* __restrict__ acc, float invn,
                           const float* __restrict__ g, const float* __restrict__ be,
                           int total, int cols) {
  int t = blockIdx.x*blockDim.x + threadIdx.x;
  if (t >= total) return;
  int c = t % cols;
  int r = t / cols;
  float mu = acc[c] * invn;
  float var = fmaxf(acc[cols+c]*invn - mu*mu, 0.f);
  float rstd = rsqrtf(var + 1e-5f);
  float v = (x[(size_t)r*xs + c] - mu) * rstd;
  if (g) v = fmaf(v, g[c], be[c]);
  y[(size_t)r*ys + c] = v;
}

// ===================== GAT =====================
__global__ void k_gat_node(const float* __restrict__ x, int K,
                           const float* __restrict__ W,
                           const float* __restrict__ as_, const float* __restrict__ ad_,
                           float* __restrict__ h, float* __restrict__ ssrc, float* __restrict__ sdst,
                           int n) {
  int i = blockIdx.x*blockDim.x + threadIdx.x;
  if (i >= n) return;
  float hv[16];
#pragma unroll
  for (int k = 0; k < 16; ++k) hv[k] = 0.f;
  for (int j = 0; j < K; ++j) {
    float xv = x[(size_t)i*K + j];
#pragma unroll
    for (int k = 0; k < 16; ++k) hv[k] = fmaf(xv, W[j*16 + k], hv[k]);
  }
  float s1 = 0.f, s2 = 0.f;
#pragma unroll
  for (int k = 0; k < 16; ++k) { s1 = fmaf(hv[k], as_[k], s1); s2 = fmaf(hv[k], ad_[k], s2); }
  float4* hp = (float4*)(h + (size_t)i*16);
  hp[0] = make_float4(hv[0],hv[1],hv[2],hv[3]);
  hp[1] = make_float4(hv[4],hv[5],hv[6],hv[7]);
  hp[2] = make_float4(hv[8],hv[9],hv[10],hv[11]);
  hp[3] = make_float4(hv[12],hv[13],hv[14],hv[15]);
  ssrc[i] = s1; sdst[i] = s2;
}

// Two-phase pass B: per (node, lane16). ew[j] precomputed; softmax denominator
// accumulated in-loop (no atomics, no exp). Only dependent load: csr[j]->h.
// Unroll x2 keeps two independent 64B h-loads in flight.
__global__ __launch_bounds__(256)
void k_gat_gather2(const int* __restrict__ rowptr, const int* __restrict__ csr,
                   const float* __restrict__ ew,
                   const float* __restrict__ h, const float* __restrict__ bias,
                   const int* __restrict__ cluster,
                   float* __restrict__ pooled, int n) {
  int g = (blockIdx.x*blockDim.x + threadIdx.x) >> 4;
  int lane = threadIdx.x & 15;
  if (g >= n) return;
  float acc = 0.f, sum = 0.f;
  int j = rowptr[g], j1 = rowptr[g+1];
  for (; j + 2 <= j1; j += 2) {
    int s0 = csr[j], s1 = csr[j+1];
    float e0 = ew[j], e1 = ew[j+1];
    float h0 = h[(size_t)s0*16 + lane];
    float h1 = h[(size_t)s1*16 + lane];
    acc = fmaf(e0, h0, acc); sum += e0;
    acc = fmaf(e1, h1, acc); sum += e1;
  }
  if (j < j1) {
    int s0 = csr[j];
    float e0 = ew[j];
    acc = fmaf(e0, h[(size_t)s0*16 + lane], acc); sum += e0;
  }
  float v = fmaf(acc, 1.f/sum, bias[lane]);
  v = fmaxf(v, 0.f);
  atomicMax((int*)(pooled + (size_t)cluster[g]*16 + lane), __float_as_int(v));
}

// Fallback (small-ws): fused gather with in-loop exp.
__global__ __launch_bounds__(256)
void k_gat_gather_pool16(const int* __restrict__ rowptr, const int* __restrict__ csr,
                         const float* __restrict__ ssrc, const float* __restrict__ sdst,
                         const float* __restrict__ h, const float* __restrict__ bias,
                         const int* __restrict__ cluster,
                         float* __restrict__ pooled, int n) {
  int g = (blockIdx.x*blockDim.x + threadIdx.x) >> 4;
  int lane = threadIdx.x & 15;
  if (g >= n) return;
  float sd = sdst[g];
  float acc = 0.f, sum = 0.f;
  int e1 = rowptr[g+1];
  for (int j = rowptr[g]; j < e1; ++j) {
    int s = csr[j];
    float l = ssrc[s] + sd;
    l = (l > 0.f) ? l : 0.2f*l;
    float e = expf(l);
    sum += e;
    acc = fmaf(e, h[(size_t)s*16 + lane], acc);
  }
  float v = fmaf(acc, 1.f/sum, bias[lane]);
  v = fmaxf(v, 0.f);
  atomicMax((int*)(pooled + (size_t)cluster[g]*16 + lane), __float_as_int(v));
}

// ===================== final GEMV =====================
__global__ __launch_bounds__(64)
void k_gemv_out(const float* __restrict__ A, const float* __restrict__ w,
                const float* __restrict__ b, float* __restrict__ out) {
  int r = blockIdx.x, l = threadIdx.x;
  float s = 0.f;
  for (int k = l; k < 384; k += 64) s = fmaf(A[(size_t)r*384 + k], w[k], s);
#pragma unroll
  for (int o = 32; o > 0; o >>= 1) s += __shfl_down(s, o);
  if (l == 0) out[r] = s + b[0];
}

// ===================== host orchestration =====================
extern "C" void kernel_launch(void* const* d_in, const int* in_sizes, int n_in,
                              void* d_out, int out_size, void* d_ws, size_t ws_size,
                              hipStream_t stream) {
  (void)n_in; (void)out_size;
  const int B = 512, N0 = 706, C1v = 512, C2v = 400;
  const int nd  = B*40;
  const int nc0 = B*N0;
  const int nc1 = B*C1v;
  const int nc2 = B*C2v;
  const int Ed  = in_sizes[40]/2;
  const int Ec0 = in_sizes[42]/2;
  const int Ec1 = in_sizes[43]/2;

  const float* drug_x = (const float*)d_in[0];
  const float* cell_x = (const float*)d_in[1];
  const float* gW1[3] = {(const float*)d_in[2],(const float*)d_in[8],(const float*)d_in[14]};
  const float* gb1[3] = {(const float*)d_in[3],(const float*)d_in[9],(const float*)d_in[15]};
  const float* gW2[3] = {(const float*)d_in[4],(const float*)d_in[10],(const float*)d_in[16]};
  const float* gb2[3] = {(const float*)d_in[5],(const float*)d_in[11],(const float*)d_in[17]};
  const float* gg [3] = {(const float*)d_in[6],(const float*)d_in[12],(const float*)d_in[18]};
  const float* gbe[3] = {(const float*)d_in[7],(const float*)d_in[13],(const float*)d_in[19]};
  const float* demb_W = (const float*)d_in[20]; const float* demb_b = (const float*)d_in[21];
  const float* gatW[2]  = {(const float*)d_in[22],(const float*)d_in[26]};
  const float* gatAS[2] = {(const float*)d_in[23],(const float*)d_in[27]};
  const float* gatAD[2] = {(const float*)d_in[24],(const float*)d_in[28]};
  const float* gatB[2]  = {(const float*)d_in[25],(const float*)d_in[29]};
  const float* cembW1 = (const float*)d_in[30]; const float* cembb1 = (const float*)d_in[31];
  const float* cembW2 = (const float*)d_in[32]; const float* cembb2 = (const float*)d_in[33];
  const float* regW1 = (const float*)d_in[34]; const float* regb1 = (const float*)d_in[35];
  const float* regW2 = (const float*)d_in[36]; const float* regb2 = (const float*)d_in[37];
  const float* regW3 = (const float*)d_in[38]; const float* regb3 = (const float*)d_in[39];
  const int* dei = (const int*)d_in[40];
  const int* ei0 = (const int*)d_in[42];
  const int* ei1 = (const int*)d_in[43];
  const int* cl0 = (const int*)d_in[44];
  const int* cl1 = (const int*)d_in[45];
  const int *dsrc = dei,       *ddst = dei + Ed;
  const int *src0 = ei0,       *dst0 = ei0 + Ec0;
  const int *src1 = ei1,       *dst1 = ei1 + Ec1;
  float* out = (float*)d_out;

  // ---- workspace layout ----
  char* base = (char*)d_ws; size_t off = 0;
  auto AL = [&](size_t bytes)->char* { char* p = base + off; off = (off + bytes + 255) & ~(size_t)255; return p; };
  float* h_cat   = (float*)AL((size_t)512*384*4);
  float* t1      = (float*)AL((size_t)512*384*4);
  float* t2      = (float*)AL((size_t)512*384*4);
  float* xd      = (float*)AL((size_t)512*384*4);
  float* cembh   = (float*)AL((size_t)512*1024*4);
  float* pooled1 = (float*)AL((size_t)nc1*16*4);
  float* pooled2 = (float*)AL((size_t)nc2*16*4);
  float* stats   = (float*)AL(256*4);
  int*   btot    = (int*)AL(512*4);
  char*  S       = base + off;
  if (ws_size < off + (size_t)56*1024*1024) return;
  // two-phase GAT needs the extra ew array (~18MB per graph, region peak ~65MB)
  const bool twophase = (ws_size >= off + (size_t)68*1024*1024);

  dim3 b256(256);
  auto NB = [&](long total) { return dim3((unsigned)((total + 255) / 256)); };

  // ================= DRUG BRANCH =================
  {
    size_t so = 0;
    auto SA = [&](size_t bytes)->char* { char* p = S + so; so = (so + bytes + 255) & ~(size_t)255; return p; };
    float* reps = (float*)SA((size_t)nd*384*4);
    float* xin  = (float*)SA((size_t)nd*128*4);
    float* hbuf = (float*)SA((size_t)nd*128*4);
    float* W1p  = (float*)SA((size_t)96*128*4);
    int* degD = (int*)SA((size_t)nd*4);
    int* rowD = (int*)SA(((size_t)nd+1)*4);
    int* csrD = (int*)SA((size_t)Ed*4);

    hipMemsetAsync(degD, 0, (size_t)nd*4, stream);
    k_deg<<<NB(Ed), b256, 0, stream>>>(ddst, Ed, 0, degD);
    k_scan_block<<<dim3(nd/1024), b256, 0, stream>>>(degD, nd, rowD, btot);
    k_scan_tot<<<1, 512, 0, stream>>>(btot, nd/1024);
    k_scan_add<<<NB(nd), b256, 0, stream>>>(rowD, btot, nd, Ed);
    hipMemsetAsync(degD, 0, (size_t)nd*4, stream);
    k_fill<<<NB(Ed), b256, 0, stream>>>(dsrc, ddst, Ed, 0, degD, rowD, csrD);

    k_pad<<<NB(96*128), b256, 0, stream>>>(gW1[0], 77, 128, W1p, 96, 128);

    const float* xsrc = drug_x; int xs = 77, F = 77, ds = 96;
    for (int L = 0; L < 3; ++L) {
      k_gin_gather<<<NB((long)nd*ds), b256, 0, stream>>>(rowD, csrD, xsrc, xs, F, xin, ds, nd);
      const float* W1 = (L == 0) ? W1p : gW1[L];
      int K1 = (L == 0) ? 96 : 128;
      k_gemm<1,0><<<dim3(2,320,1), b256, 0, stream>>>(xin, ds, W1, 128, gb1[L], hbuf, 128, K1);
      k_gemm<1,0><<<dim3(2,320,1), b256, 0, stream>>>(hbuf, 128, gW2[L], 128, gb2[L], xin, 128, 128);
      hipMemsetAsync(stats, 0, 256*4, stream);
      k_bn_stats<<<dim3(160), b256, 0, stream>>>(xin, nd, 128, stats);
      k_bn_apply<<<NB((long)nd*128), b256, 0, stream>>>(xin, 128, reps + L*128, 384,
                                                        stats, 1.f/nd, gg[L], gbe[L], nd*128, 128);
      xsrc = reps + L*128; xs = 384; F = 128; ds = 128;
    }
    k_drug_pool<<<dim3(512), dim3(384), 0, stream>>>(reps, xd);
    hipMemsetAsync(h_cat, 0, (size_t)512*384*4, stream);
    k_gemm<1,0><<<dim3(2,8,1), b256, 0, stream>>>(xd, 384, demb_W, 128, demb_b, h_cat, 384, 384);
  }

  // ================= CELL BRANCH (one GAT layer per block scope) =================
  for (int L = 0; L < 2; ++L) {
    const int n    = (L == 0) ? nc0 : nc1;
    const int E    = (L == 0) ? Ec0 : Ec1;
    const int nout = (L == 0) ? nc1 : nc2;
    const int* esrc = (L == 0) ? src0 : src1;
    const int* edst = (L == 0) ? dst0 : dst1;
    const int* clus = (L == 0) ? cl0 : cl1;
    const float* xin = (L == 0) ? cell_x : pooled1;
    const int Kin = (L == 0) ? 3 : 16;
    float* pooled = (L == 0) ? pooled1 : pooled2;

    size_t so = 0;
    auto SA = [&](size_t bytes)->char* { char* p = S + so; so = (so + bytes + 255) & ~(size_t)255; return p; };
    float* h  = (float*)SA((size_t)n*16*4);
    float* ss = (float*)SA((size_t)n*4);
    float* sd = (float*)SA((size_t)n*4);
    int* deg  = (int*)SA((size_t)n*4);
    int* row  = (int*)SA(((size_t)n+1)*4);
    int* csr  = (int*)SA((size_t)(E+n)*4);
    float* ew = twophase ? (float*)SA((size_t)(E+n)*4) : nullptr;

    k_gat_node<<<NB(n), b256, 0, stream>>>(xin, Kin, gatW[L], gatAS[L], gatAD[L], h, ss, sd, n);
    hipMemsetAsync(deg, 0, (size_t)n*4, stream);
    k_deg<<<NB((long)E+n), b256, 0, stream>>>(edst, E, n, deg);
    k_scan_block<<<dim3((n+1023)/1024), b256, 0, stream>>>(deg, n, row, btot);
    k_scan_tot<<<1, 512, 0, stream>>>(btot, (n+1023)/1024);
    k_scan_add<<<NB(n), b256, 0, stream>>>(row, btot, n, E+n);
    hipMemsetAsync(deg, 0, (size_t)n*4, stream);
    hipMemsetAsync(pooled, 0, (size_t)nout*16*4, stream);
    if (twophase) {
      k_fill_gat<<<NB((long)E+n), b256, 0, stream>>>(esrc, edst, E, n, deg, row, ss, sd, csr, ew);
      k_gat_gather2<<<NB((long)n*16), b256, 0, stream>>>(row, csr, ew, h, gatB[L], clus, pooled, n);
    } else {
      k_fill<<<NB((long)E+n), b256, 0, stream>>>(esrc, edst, E, n, deg, row, csr);
      k_gat_gather_pool16<<<NB((long)n*16), b256, 0, stream>>>(row, csr, ss, sd, h, gatB[L], clus, pooled, n);
    }
    hipMemsetAsync(stats, 0, 256*4, stream);
    k_bn_stats<<<dim3(256), b256, 0, stream>>>(pooled, nout, 16, stats);
    k_bn_apply<<<NB((long)nout*16), b256, 0, stream>>>(pooled, 16, pooled, 16,
                                                       stats, 1.f/nout, nullptr, nullptr, nout*16, 16);
  }

  // ================= cell embedding MLP =================
  hipMemsetAsync(cembh, 0, (size_t)512*1024*4, stream);
  k_gemm<0,1><<<dim3(16,8,8), b256, 0, stream>>>(pooled2, 6400, cembW1, 1024, nullptr, cembh, 1024, 800);
  k_bias_act<1><<<NB((long)512*1024), b256, 0, stream>>>(cembh, 1024, cembb1, 512, 1024);
  k_gemm<0,1><<<dim3(4,8,8), b256, 0, stream>>>(cembh, 1024, cembW2, 256, nullptr, h_cat + 128, 384, 128);
  k_bias_act<1><<<NB((long)512*256), b256, 0, stream>>>(h_cat + 128, 384, cembb2, 512, 256);

  // ================= regressor =================
  hipMemsetAsync(t1, 0, (size_t)512*384*4, stream);
  k_gemm<0,1><<<dim3(6,8,4), b256, 0, stream>>>(h_cat, 384, regW1, 384, nullptr, t1, 384, 96);
  k_bias_act<2><<<NB((long)512*384), b256, 0, stream>>>(t1, 384, regb1, 512, 384);
  hipMemsetAsync(t2, 0, (size_t)512*384*4, stream);
  k_gemm<0,1><<<dim3(6,8,4), b256, 0, stream>>>(t1, 384, regW2, 384, nullptr, t2, 384, 96);
  k_bias_act<2><<<NB((long)512*384), b256, 0, stream>>>(t2, 384, regb2, 512, 384);
  k_gemv_out<<<dim3(512), dim3(64), 0, stream>>>(t2, regW3, regb3, out);
}